// Round 3
// baseline (3115.156 us; speedup 1.0000x reference)
//
#include <hip/hip_runtime.h>
#include <math.h>

#define BB 64
#define II 2048
#define DD 16
#define NN 32
#define EE 32

// Padded LDS row stride for one (n) row of W[i] (D*E = 512 floats + 4 pad)
// breaks the 32-way bank conflict on cross-row reads while keeping 16B alignment.
#define WROW 516
#define WROW4 129   // float4 stride

// ---------------------------------------------------------------------------
// k_weighted: s[b,n,e] += sum_i c[b,i,n] * (sum_d x[b,i,d] * W[i,n,d,e])
// Block: 16 i's x 8 n's x all b x all e. Grid: (128, 4).
// Thread t: n = n0 + (t&7), b0 = t>>3 (0..31), b1 = b0+32. acc[2][32] in regs.
// ---------------------------------------------------------------------------
template<int UNIFORM>
__global__ __launch_bounds__(256) void k_weighted(
    const float* __restrict__ x,      // [B][I][D]
    const float* __restrict__ Wg,     // [I][N][D][E]
    const float* __restrict__ c_buf,  // [B][I][N] (unused if UNIFORM)
    float* __restrict__ s_buf)        // [B][N][E]
{
    __shared__ float Wl[8 * WROW];
    __shared__ float xl[BB][DD];
    __shared__ float cl[BB][8];

    const int ic = blockIdx.x;        // 0..127
    const int n0 = blockIdx.y * 8;    // 0,8,16,24
    const int t  = threadIdx.x;
    const int nn = t & 7;
    const int b0 = t >> 3;
    const int b1 = b0 + 32;

    float acc0[EE], acc1[EE];
#pragma unroll
    for (int e = 0; e < EE; ++e) { acc0[e] = 0.f; acc1[e] = 0.f; }

    for (int ii = 0; ii < 16; ++ii) {
        const int i = ic * 16 + ii;
        __syncthreads();  // protect LDS reuse from previous iteration
        // stage W[i, n0:n0+8, :, :]  (8 rows x 128 float4)
        const float4* Wg4 = (const float4*)(Wg + ((size_t)i * NN + n0) * (DD * EE));
        float4* Wl4 = (float4*)Wl;
#pragma unroll
        for (int k = 0; k < 4; ++k) {
            int j = t + 256 * k;           // 0..1023
            int n = j >> 7;                // 0..7
            Wl4[n * WROW4 + (j & 127)] = Wg4[j];
        }
        // stage x[:, i, :]
        {
            int b = t >> 2, q = t & 3;
            ((float4*)&xl[b][0])[q] = ((const float4*)(x + ((size_t)b * II + i) * DD))[q];
        }
        // stage c[:, i, n0:n0+8]  — all 256 threads: 4 float2 per batch row
        if (!UNIFORM) {
            int b = t >> 2, q = t & 3;
            ((float2*)&cl[b][0])[q] =
                ((const float2*)(c_buf + ((size_t)b * II + i) * NN + n0))[q];
        }
        __syncthreads();

        float c0, c1;
        if (UNIFORM) { c0 = 1.0f / 32.0f; c1 = c0; }
        else         { c0 = cl[b0][nn];   c1 = cl[b1][nn]; }

#pragma unroll
        for (int d = 0; d < DD; ++d) {
            float cx0 = c0 * xl[b0][d];
            float cx1 = c1 * xl[b1][d];
            const float4* wr = (const float4*)&Wl[nn * WROW + d * EE];
#pragma unroll
            for (int s = 0; s < 8; ++s) {
                float4 w = wr[s];
                acc0[4*s+0] += cx0 * w.x; acc0[4*s+1] += cx0 * w.y;
                acc0[4*s+2] += cx0 * w.z; acc0[4*s+3] += cx0 * w.w;
                acc1[4*s+0] += cx1 * w.x; acc1[4*s+1] += cx1 * w.y;
                acc1[4*s+2] += cx1 * w.z; acc1[4*s+3] += cx1 * w.w;
            }
        }
    }

    const int n = n0 + nn;
    float* s0 = s_buf + ((size_t)b0 * NN + n) * EE;
    float* s1 = s_buf + ((size_t)b1 * NN + n) * EE;
#pragma unroll
    for (int e = 0; e < EE; ++e) {
        atomicAdd(s0 + e, acc0[e]);
        atomicAdd(s1 + e, acc1[e]);
    }
}

// ---------------------------------------------------------------------------
// k_logits: c[b,i,n] = softmax_n( sum_e (sum_d x[b,i,d] W[i,n,d,e]) * v[b,n,e] )
// v is v0 for round 1 and (v0+v1) for round 2 (b-logit telescoping).
// Block: one i, all b,n. Two n-phases of 16 rows to keep LDS under 64 KB.
// ---------------------------------------------------------------------------
__global__ __launch_bounds__(256) void k_logits(
    const float* __restrict__ x,      // [B][I][D]
    const float* __restrict__ Wg,     // [I][N][D][E]
    const float* __restrict__ v,      // [B][N][E]
    float* __restrict__ c_buf)        // [B][I][N]
{
    __shared__ float Wl[16 * WROW];   // 33 KB
    __shared__ float xl[BB][DD];      // 4 KB
    __shared__ float bl[BB][NN];      // 8 KB

    const int i = blockIdx.x;
    const int t = threadIdx.x;

    // stage x[:, i, :]
    {
        int b = t >> 2, q = t & 3;
        ((float4*)&xl[b][0])[q] = ((const float4*)(x + ((size_t)b * II + i) * DD))[q];
    }

    const float4* Wg4 = (const float4*)(Wg + (size_t)i * (NN * DD * EE));

    for (int ph = 0; ph < 2; ++ph) {
        __syncthreads();  // covers x stage + Wl reuse across phases
        // stage rows n = ph*16 .. ph*16+15 (16 x 128 float4)
        float4* Wl4 = (float4*)Wl;
#pragma unroll
        for (int k = 0; k < 8; ++k) {
            int j = t + 256 * k;          // 0..2047
            int n = j >> 7;               // 0..15
            Wl4[n * WROW4 + (j & 127)] = Wg4[(ph * 16 + n) * 128 + (j & 127)];
        }
        __syncthreads();

        const int n_loc = t & 15;
        const int n = ph * 16 + n_loc;
        const int bb = t >> 4;            // 0..15
#pragma unroll
        for (int g = 0; g < 2; ++g) {
            const int b0 = bb + 32 * g;
            const int b1 = b0 + 16;
            float u0[EE], u1[EE];
#pragma unroll
            for (int e = 0; e < EE; ++e) { u0[e] = 0.f; u1[e] = 0.f; }
#pragma unroll
            for (int d = 0; d < DD; ++d) {
                float x0 = xl[b0][d], x1 = xl[b1][d];
                const float4* wr = (const float4*)&Wl[n_loc * WROW + d * EE];
#pragma unroll
                for (int s = 0; s < 8; ++s) {
                    float4 w = wr[s];
                    u0[4*s+0] += x0 * w.x; u0[4*s+1] += x0 * w.y;
                    u0[4*s+2] += x0 * w.z; u0[4*s+3] += x0 * w.w;
                    u1[4*s+0] += x1 * w.x; u1[4*s+1] += x1 * w.y;
                    u1[4*s+2] += x1 * w.z; u1[4*s+3] += x1 * w.w;
                }
            }
            // A = u . v[b,n,:]
            const float4* v0p = (const float4*)(v + ((size_t)b0 * NN + n) * EE);
            const float4* v1p = (const float4*)(v + ((size_t)b1 * NN + n) * EE);
            float a0 = 0.f, a1 = 0.f;
#pragma unroll
            for (int s = 0; s < 8; ++s) {
                float4 w0 = v0p[s], w1 = v1p[s];
                a0 += u0[4*s]*w0.x + u0[4*s+1]*w0.y + u0[4*s+2]*w0.z + u0[4*s+3]*w0.w;
                a1 += u1[4*s]*w1.x + u1[4*s+1]*w1.y + u1[4*s+2]*w1.z + u1[4*s+3]*w1.w;
            }
            bl[b0][n] = a0;
            bl[b1][n] = a1;
        }
    }
    __syncthreads();

    // softmax over n: thread handles n = t&31, b = (t>>5) + 8k
    {
        const int n = t & 31;
        const int bb2 = t >> 5;
#pragma unroll
        for (int k = 0; k < 8; ++k) {
            const int b = bb2 + 8 * k;
            float val = bl[b][n];
            float m = val;
            for (int msk = 16; msk >= 1; msk >>= 1) m = fmaxf(m, __shfl_xor(m, msk));
            float p = __expf(val - m);
            float ssum = p;
            for (int msk = 16; msk >= 1; msk >>= 1) ssum += __shfl_xor(ssum, msk);
            c_buf[((size_t)b * II + i) * NN + n] = p / ssum;
        }
    }
}

// ---------------------------------------------------------------------------
// k_squash: v = squash(s) over E; ACCUM=1 adds into vout (builds v0+v1).
// ---------------------------------------------------------------------------
template<int ACCUM>
__global__ __launch_bounds__(256) void k_squash(
    const float* __restrict__ s, float* __restrict__ vout)
{
    const int tid = blockIdx.x * 256 + threadIdx.x;  // 0..65535, e = lane&31
    float val = s[tid];
    float sq = val * val;
    for (int msk = 16; msk >= 1; msk >>= 1) sq += __shfl_xor(sq, msk);
    float scale = sq / (1.f + sq) * rsqrtf(sq + 1e-7f);
    float r = scale * val;
    if (ACCUM) vout[tid] += r; else vout[tid] = r;
}

// ---------------------------------------------------------------------------
extern "C" void kernel_launch(void* const* d_in, const int* in_sizes, int n_in,
                              void* d_out, int out_size, void* d_ws, size_t ws_size,
                              hipStream_t stream)
{
    const float* x = (const float*)d_in[0];
    const float* W = (const float*)d_in[1];
    float* ws    = (float*)d_ws;
    float* c_buf = ws;                         // 4,194,304 floats (16 MB)
    float* s_buf = ws + 4194304;               // 65,536 floats
    float* v_buf = ws + 4194304 + 65536;       // 65,536 floats
    float* out   = (float*)d_out;

    // round 0: c uniform = 1/32
    hipMemsetAsync(s_buf, 0, 65536 * sizeof(float), stream);
    k_weighted<1><<<dim3(128, 4), 256, 0, stream>>>(x, W, nullptr, s_buf);
    k_squash<0><<<256, 256, 0, stream>>>(s_buf, v_buf);          // v_buf = v0

    // round 1: logits vs v0
    k_logits<<<2048, 256, 0, stream>>>(x, W, v_buf, c_buf);
    hipMemsetAsync(s_buf, 0, 65536 * sizeof(float), stream);
    k_weighted<0><<<dim3(128, 4), 256, 0, stream>>>(x, W, c_buf, s_buf);
    k_squash<1><<<256, 256, 0, stream>>>(s_buf, v_buf);          // v_buf = v0+v1

    // round 2: logits vs (v0+v1)  [b2 = sum_e u_hat*(v0+v1)]
    k_logits<<<2048, 256, 0, stream>>>(x, W, v_buf, c_buf);
    hipMemsetAsync(s_buf, 0, 65536 * sizeof(float), stream);
    k_weighted<0><<<dim3(128, 4), 256, 0, stream>>>(x, W, c_buf, s_buf);
    k_squash<0><<<256, 256, 0, stream>>>(s_buf, out);            // final v2
}

// Round 4
// 2505.459 us; speedup vs baseline: 1.2433x; 1.2433x over previous
//
#include <hip/hip_runtime.h>
#include <hip/hip_bf16.h>
#include <math.h>

#define BB 64
#define II 2048
#define DD 16
#define NN 32
#define EE 32

// Padded LDS row stride for one (n) row of W[i] (D*E = 512 floats + 4 pad)
#define WROW 516
#define WROW4 129   // float4 stride

typedef __bf16 bf16x8 __attribute__((ext_vector_type(8)));
typedef float  f32x16 __attribute__((ext_vector_type(16)));

static __device__ inline short f2bf_bits(float f) {
    union { __bf16 h; short s; } u; u.h = (__bf16)f; return u.s;
}

// ---------------------------------------------------------------------------
// k_weighted: s[b,n,e] += sum_i c[b,i,n] * (sum_d x[b,i,d] * W[i,n,d,e])
// (unchanged from round 2 — VALU path; MFMA rewrite is next round's target)
// ---------------------------------------------------------------------------
template<int UNIFORM>
__global__ __launch_bounds__(256) void k_weighted(
    const float* __restrict__ x,      // [B][I][D]
    const float* __restrict__ Wg,     // [I][N][D][E]
    const float* __restrict__ c_buf,  // [B][I][N] (unused if UNIFORM)
    float* __restrict__ s_buf)        // [B][N][E]
{
    __shared__ float Wl[8 * WROW];
    __shared__ float xl[BB][DD];
    __shared__ float cl[BB][8];

    const int ic = blockIdx.x;        // 0..127
    const int n0 = blockIdx.y * 8;    // 0,8,16,24
    const int t  = threadIdx.x;
    const int nn = t & 7;
    const int b0 = t >> 3;
    const int b1 = b0 + 32;

    float acc0[EE], acc1[EE];
#pragma unroll
    for (int e = 0; e < EE; ++e) { acc0[e] = 0.f; acc1[e] = 0.f; }

    for (int ii = 0; ii < 16; ++ii) {
        const int i = ic * 16 + ii;
        __syncthreads();
        const float4* Wg4 = (const float4*)(Wg + ((size_t)i * NN + n0) * (DD * EE));
        float4* Wl4 = (float4*)Wl;
#pragma unroll
        for (int k = 0; k < 4; ++k) {
            int j = t + 256 * k;
            int n = j >> 7;
            Wl4[n * WROW4 + (j & 127)] = Wg4[j];
        }
        {
            int b = t >> 2, q = t & 3;
            ((float4*)&xl[b][0])[q] = ((const float4*)(x + ((size_t)b * II + i) * DD))[q];
        }
        if (!UNIFORM) {
            int b = t >> 2, q = t & 3;
            ((float2*)&cl[b][0])[q] =
                ((const float2*)(c_buf + ((size_t)b * II + i) * NN + n0))[q];
        }
        __syncthreads();

        float c0, c1;
        if (UNIFORM) { c0 = 1.0f / 32.0f; c1 = c0; }
        else         { c0 = cl[b0][nn];   c1 = cl[b1][nn]; }

#pragma unroll
        for (int d = 0; d < DD; ++d) {
            float cx0 = c0 * xl[b0][d];
            float cx1 = c1 * xl[b1][d];
            const float4* wr = (const float4*)&Wl[nn * WROW + d * EE];
#pragma unroll
            for (int s = 0; s < 8; ++s) {
                float4 w = wr[s];
                acc0[4*s+0] += cx0 * w.x; acc0[4*s+1] += cx0 * w.y;
                acc0[4*s+2] += cx0 * w.z; acc0[4*s+3] += cx0 * w.w;
                acc1[4*s+0] += cx1 * w.x; acc1[4*s+1] += cx1 * w.y;
                acc1[4*s+2] += cx1 * w.z; acc1[4*s+3] += cx1 * w.w;
            }
        }
    }

    const int n = n0 + nn;
    float* s0 = s_buf + ((size_t)b0 * NN + n) * EE;
    float* s1 = s_buf + ((size_t)b1 * NN + n) * EE;
#pragma unroll
    for (int e = 0; e < EE; ++e) {
        atomicAdd(s0 + e, acc0[e]);
        atomicAdd(s1 + e, acc1[e]);
    }
}

// ---------------------------------------------------------------------------
// k_logits_mfma: c[b,i,n] = softmax_n( sum_e u_hat[b,i,n,e] * v[b,n,e] )
// u_hat recomputed via MFMA:  uT[e, b] = sum_d W[i,n,d,e] * x[b,i,d]
//   A = W-slice  (M=32 rows = e, K=16 = d): lane row=l&31, k=8*(l>>5)+j
//   B = x        (K=16 = d, N=32 cols = b): lane col=l&31, k contiguous
//   C (verified): col = lane&31 (=b), row = (reg&3)+8*(reg>>2)+4*(lane>>5) (=e)
// => per lane: b fixed, 16 e-values in regs -> lane-local dot with v,
//    one shfl_xor(32) to merge e-halves. Softmax per b in LDS.
// Grid: 512 blocks x 4 i's. Waves: w owns n = w*8..w*8+7.
// ---------------------------------------------------------------------------
__global__ __launch_bounds__(256) void k_logits_mfma(
    const float* __restrict__ x,      // [B][I][D]
    const float* __restrict__ Wg,     // [I][N][D][E]
    const float* __restrict__ v,      // [B][N][E]
    float* __restrict__ c_buf)        // [B][I][N]
{
    __shared__ short xl[BB][24];      // bf16 bits, padded stride (48 B rows)
    __shared__ float al[BB][33];      // logits, padded

    const int t      = threadIdx.x;
    const int w      = t >> 6;        // wave 0..3
    const int lane31 = t & 31;
    const int half   = (t >> 5) & 1;

    for (int it = 0; it < 4; ++it) {
        const int i = blockIdx.x * 4 + it;

        // stage x[:, i, :] as bf16 into xl
        {
            const int b = t >> 2, dg = (t & 3) * 4;
            const float4 xv = *(const float4*)(x + ((size_t)b * II + i) * DD + dg);
            short4 s;
            s.x = f2bf_bits(xv.x); s.y = f2bf_bits(xv.y);
            s.z = f2bf_bits(xv.z); s.w = f2bf_bits(xv.w);
            *(short4*)&xl[b][dg] = s;
        }
        __syncthreads();

        // B-frags (x): lane = col b, 8 contiguous k (d) bf16  [16B-aligned]
        const bf16x8 bx0 = *(const bf16x8*)&xl[lane31][8 * half];
        const bf16x8 bx1 = *(const bf16x8*)&xl[32 + lane31][8 * half];

        for (int ci = 0; ci < 8; ++ci) {
            const int n = w * 8 + ci;
            // A-frag (W): row = e = lane31, k = d = 8*half + j (stride EE)
            const float* wp = Wg + (((size_t)i * NN + n) * DD + 8 * half) * EE + lane31;
            bf16x8 af;
#pragma unroll
            for (int j = 0; j < 8; ++j) af[j] = (__bf16)wp[j * EE];

#pragma unroll
            for (int m = 0; m < 2; ++m) {
                f32x16 cf = __builtin_amdgcn_mfma_f32_32x32x16_bf16(
                    af, (m ? bx1 : bx0), (f32x16)(0.0f), 0, 0, 0);
                // dot with v[b, n, e]: b = 32m+lane31, e = (reg&3)+8*(reg>>2)+4*half
                const float* vp = v + ((size_t)(32 * m + lane31) * NN + n) * EE + 4 * half;
                float acc = 0.f;
#pragma unroll
                for (int r2 = 0; r2 < 4; ++r2) {
                    const float4 vv = *(const float4*)(vp + 8 * r2);
                    acc += cf[r2 * 4 + 0] * vv.x + cf[r2 * 4 + 1] * vv.y
                         + cf[r2 * 4 + 2] * vv.z + cf[r2 * 4 + 3] * vv.w;
                }
                acc += __shfl_xor(acc, 32);           // merge e-halves
                if (half == 0) al[32 * m + lane31][n] = acc;
            }
        }
        __syncthreads();

        // softmax over n per b (threads 0..63), write c[b][i][0..31]
        if (t < BB) {
            float a[NN]; float mx = -1e30f;
#pragma unroll
            for (int n = 0; n < NN; ++n) { a[n] = al[t][n]; mx = fmaxf(mx, a[n]); }
            float ssum = 0.f;
#pragma unroll
            for (int n = 0; n < NN; ++n) { a[n] = __expf(a[n] - mx); ssum += a[n]; }
            const float inv = 1.f / ssum;
            float* cp = c_buf + ((size_t)t * II + i) * NN;
#pragma unroll
            for (int n = 0; n < NN; ++n) cp[n] = a[n] * inv;
        }
        __syncthreads();
    }
}

// ---------------------------------------------------------------------------
// k_squash: v = squash(s) over E; ACCUM=1 adds into vout (builds v0+v1).
// ---------------------------------------------------------------------------
template<int ACCUM>
__global__ __launch_bounds__(256) void k_squash(
    const float* __restrict__ s, float* __restrict__ vout)
{
    const int tid = blockIdx.x * 256 + threadIdx.x;  // e = lane&31
    float val = s[tid];
    float sq = val * val;
    for (int msk = 16; msk >= 1; msk >>= 1) sq += __shfl_xor(sq, msk);
    float scale = sq / (1.f + sq) * rsqrtf(sq + 1e-7f);
    float r = scale * val;
    if (ACCUM) vout[tid] += r; else vout[tid] = r;
}

// ---------------------------------------------------------------------------
extern "C" void kernel_launch(void* const* d_in, const int* in_sizes, int n_in,
                              void* d_out, int out_size, void* d_ws, size_t ws_size,
                              hipStream_t stream)
{
    const float* x = (const float*)d_in[0];
    const float* W = (const float*)d_in[1];
    float* ws    = (float*)d_ws;
    float* c_buf = ws;                         // 16 MB
    float* s_buf = ws + 4194304;               // 65,536 floats
    float* v_buf = ws + 4194304 + 65536;       // 65,536 floats
    float* out   = (float*)d_out;

    // round 0: c uniform = 1/32
    hipMemsetAsync(s_buf, 0, 65536 * sizeof(float), stream);
    k_weighted<1><<<dim3(128, 4), 256, 0, stream>>>(x, W, nullptr, s_buf);
    k_squash<0><<<256, 256, 0, stream>>>(s_buf, v_buf);          // v_buf = v0

    // round 1: logits vs v0
    k_logits_mfma<<<512, 256, 0, stream>>>(x, W, v_buf, c_buf);
    hipMemsetAsync(s_buf, 0, 65536 * sizeof(float), stream);
    k_weighted<0><<<dim3(128, 4), 256, 0, stream>>>(x, W, c_buf, s_buf);
    k_squash<1><<<256, 256, 0, stream>>>(s_buf, v_buf);          // v_buf = v0+v1

    // round 2: logits vs (v0+v1)  [b2 = sum_e u_hat*(v0+v1)]
    k_logits_mfma<<<512, 256, 0, stream>>>(x, W, v_buf, c_buf);
    hipMemsetAsync(s_buf, 0, 65536 * sizeof(float), stream);
    k_weighted<0><<<dim3(128, 4), 256, 0, stream>>>(x, W, c_buf, s_buf);
    k_squash<0><<<256, 256, 0, stream>>>(s_buf, out);            // final v2
}

// Round 5
// 425.544 us; speedup vs baseline: 7.3204x; 5.8877x over previous
//
#include <hip/hip_runtime.h>
#include <hip/hip_bf16.h>
#include <math.h>

#define BB 64
#define II 2048
#define DD 16
#define NN 32
#define EE 32
#define ICHUNK 64          // i's per k_weighted block
#define NICB (II/ICHUNK)   // 32 partial slabs

typedef __bf16 bf16x8 __attribute__((ext_vector_type(8)));
typedef float  f32x16 __attribute__((ext_vector_type(16)));

static __device__ inline short f2bf_bits(float f) {
    union { __bf16 h; short s; } u; u.h = (__bf16)f; return u.s;
}

// ---------------------------------------------------------------------------
// k_weighted_mfma: partial[ic,n,b,e] = sum_{i in chunk, d} bf16(c[b,i,n]*x[b,i,d])
//                                      * bf16(W[i,n,d,e])
// MFMA 32x32x16 bf16: A = c*x (row=b=lane31 [+32/tile], k=d=8*half+j),
//                     B = W   (col=e=lane31, k=d=8*half+j),
//                     C: col=e=lane31, row b=(reg&3)+8*(reg>>2)+4*half (+32/tile)
// Same fragment mappings as the HW-verified k_logits_mfma. No atomics.
// Grid (32 ic, 8 ng), 256 thr = 4 waves, wave owns n = ng*4 + w.
// ---------------------------------------------------------------------------
template<int UNIFORM>
__global__ __launch_bounds__(256) void k_weighted_mfma(
    const float* __restrict__ x,      // [B][I][D]
    const float* __restrict__ Wg,     // [I][N][D][E]
    const float* __restrict__ c_buf,  // [I][N][B]  (ignored if UNIFORM)
    float* __restrict__ partial)      // [NICB][N][B][E]
{
    __shared__ short xl[8 * 64 * 24]; // chunk of 8 i's: [il][b][d, pad 24] bf16 bits

    const int ic     = blockIdx.x;    // 0..31
    const int ng     = blockIdx.y;    // 0..7
    const int t      = threadIdx.x;
    const int w      = t >> 6;
    const int n      = ng * 4 + w;
    const int lane31 = t & 31;
    const int half   = (t >> 5) & 1;
    const int i0     = ic * ICHUNK;

    f32x16 acc0 = (f32x16)(0.0f), acc1 = (f32x16)(0.0f);

    for (int c8 = 0; c8 < ICHUNK / 8; ++c8) {
        const int ib = i0 + c8 * 8;
        __syncthreads();
        // stage x[:, ib..ib+8, :] as bf16 (thread: b=t>>2, dg=(t&3)*4, loop il)
        {
            const int b = t >> 2, dg = (t & 3) * 4;
#pragma unroll
            for (int il = 0; il < 8; ++il) {
                const float4 xv = *(const float4*)(x + ((size_t)b * II + ib + il) * DD + dg);
                short4 s4;
                s4.x = f2bf_bits(xv.x); s4.y = f2bf_bits(xv.y);
                s4.z = f2bf_bits(xv.z); s4.w = f2bf_bits(xv.w);
                *(short4*)&xl[((il * 64 + b) * 24) + dg] = s4;
            }
        }
        __syncthreads();

        // prefetch c for the chunk (per-lane scalar, coalesced 128B per tile)
        float cf0[8], cf1[8];
        if (!UNIFORM) {
#pragma unroll
            for (int il = 0; il < 8; ++il) {
                const float* cp = c_buf + ((size_t)(ib + il) * NN + n) * BB + lane31;
                cf0[il] = cp[0];
                cf1[il] = cp[32];
            }
        }

#pragma unroll
        for (int il = 0; il < 8; ++il) {
            const int i = ib + il;
            // x fragments for both b-tiles (16B-aligned b128 reads)
            const bf16x8 xr0 = *(const bf16x8*)&xl[(il * 64 + lane31) * 24 + 8 * half];
            const bf16x8 xr1 = *(const bf16x8*)&xl[(il * 64 + 32 + lane31) * 24 + 8 * half];
            // W fragment (col = e = lane31, k = d = 8*half + j)
            const float* wp = Wg + (((size_t)i * NN + n) * DD + 8 * half) * EE + lane31;
            bf16x8 bw;
#pragma unroll
            for (int j = 0; j < 8; ++j) bw[j] = (__bf16)wp[j * EE];
            // A = bf16(c * x)
            const float c0 = UNIFORM ? 0.03125f : cf0[il];
            const float c1 = UNIFORM ? 0.03125f : cf1[il];
            bf16x8 a0, a1;
#pragma unroll
            for (int j = 0; j < 8; ++j) {
                a0[j] = (__bf16)(c0 * (float)xr0[j]);
                a1[j] = (__bf16)(c1 * (float)xr1[j]);
            }
            acc0 = __builtin_amdgcn_mfma_f32_32x32x16_bf16(a0, bw, acc0, 0, 0, 0);
            acc1 = __builtin_amdgcn_mfma_f32_32x32x16_bf16(a1, bw, acc1, 0, 0, 0);
        }
    }

    // store C-frags: row b = (reg&3)+8*(reg>>2)+4*half (+32 for tile 1), col e = lane31
    float* pp = partial + ((size_t)ic * NN + n) * BB * EE + lane31;
#pragma unroll
    for (int reg = 0; reg < 16; ++reg) {
        const int r = (reg & 3) + 8 * (reg >> 2) + 4 * half;
        pp[(size_t)r * EE]        = acc0[reg];
        pp[(size_t)(r + 32) * EE] = acc1[reg];
    }
}

// ---------------------------------------------------------------------------
// k_logits_mfma: c[i,n,b] = softmax_n( sum_e u_hat[b,i,n,e] * v[b,n,e] )
// (unchanged from round 3 except c_buf layout now [I][N][B], coalesced per n)
// ---------------------------------------------------------------------------
__global__ __launch_bounds__(256) void k_logits_mfma(
    const float* __restrict__ x,      // [B][I][D]
    const float* __restrict__ Wg,     // [I][N][D][E]
    const float* __restrict__ v,      // [B][N][E]
    float* __restrict__ c_buf)        // [I][N][B]
{
    __shared__ short xl[BB][24];      // bf16 bits, padded stride
    __shared__ float al[BB][33];      // logits, padded

    const int t      = threadIdx.x;
    const int w      = t >> 6;        // wave 0..3
    const int lane31 = t & 31;
    const int half   = (t >> 5) & 1;

    for (int it = 0; it < 4; ++it) {
        const int i = blockIdx.x * 4 + it;

        // stage x[:, i, :] as bf16
        {
            const int b = t >> 2, dg = (t & 3) * 4;
            const float4 xv = *(const float4*)(x + ((size_t)b * II + i) * DD + dg);
            short4 s4;
            s4.x = f2bf_bits(xv.x); s4.y = f2bf_bits(xv.y);
            s4.z = f2bf_bits(xv.z); s4.w = f2bf_bits(xv.w);
            *(short4*)&xl[b][dg] = s4;
        }
        __syncthreads();

        const bf16x8 bx0 = *(const bf16x8*)&xl[lane31][8 * half];
        const bf16x8 bx1 = *(const bf16x8*)&xl[32 + lane31][8 * half];

        for (int ci = 0; ci < 8; ++ci) {
            const int n = w * 8 + ci;
            const float* wp = Wg + (((size_t)i * NN + n) * DD + 8 * half) * EE + lane31;
            bf16x8 af;
#pragma unroll
            for (int j = 0; j < 8; ++j) af[j] = (__bf16)wp[j * EE];

#pragma unroll
            for (int m = 0; m < 2; ++m) {
                f32x16 cf = __builtin_amdgcn_mfma_f32_32x32x16_bf16(
                    af, (m ? bx1 : bx0), (f32x16)(0.0f), 0, 0, 0);
                const float* vp = v + ((size_t)(32 * m + lane31) * NN + n) * EE + 4 * half;
                float acc = 0.f;
#pragma unroll
                for (int r2 = 0; r2 < 4; ++r2) {
                    const float4 vv = *(const float4*)(vp + 8 * r2);
                    acc += cf[r2 * 4 + 0] * vv.x + cf[r2 * 4 + 1] * vv.y
                         + cf[r2 * 4 + 2] * vv.z + cf[r2 * 4 + 3] * vv.w;
                }
                acc += __shfl_xor(acc, 32);           // merge e-halves
                if (half == 0) al[32 * m + lane31][n] = acc;
            }
        }
        __syncthreads();

        // softmax over n per b; write c[i][n][b] (coalesced across t per n)
        if (t < BB) {
            float a[NN]; float mx = -1e30f;
#pragma unroll
            for (int nn2 = 0; nn2 < NN; ++nn2) { a[nn2] = al[t][nn2]; mx = fmaxf(mx, a[nn2]); }
            float ssum = 0.f;
#pragma unroll
            for (int nn2 = 0; nn2 < NN; ++nn2) { a[nn2] = __expf(a[nn2] - mx); ssum += a[nn2]; }
            const float inv = 1.f / ssum;
            float* cp = c_buf + (size_t)i * NN * BB + t;
#pragma unroll
            for (int nn2 = 0; nn2 < NN; ++nn2) cp[(size_t)nn2 * BB] = a[nn2] * inv;
        }
        __syncthreads();
    }
}

// ---------------------------------------------------------------------------
// k_squash_red: s = sum_ic partial[ic]; v = squash(s). tid = n*2048+b*32+e.
// ACCUM=1 adds into vout (builds v0+v1). Writes vout[b][n][e].
// ---------------------------------------------------------------------------
template<int ACCUM>
__global__ __launch_bounds__(256) void k_squash_red(
    const float* __restrict__ partial, float* __restrict__ vout)
{
    const int tid = blockIdx.x * 256 + threadIdx.x;   // 0..65535
    float s = 0.f;
#pragma unroll 4
    for (int ic = 0; ic < NICB; ++ic) s += partial[(size_t)ic * (NN * BB * EE) + tid];
    float sq = s * s;
    for (int msk = 16; msk >= 1; msk >>= 1) sq += __shfl_xor(sq, msk);
    const float scale = sq / (1.f + sq) * rsqrtf(sq + 1e-7f);
    const float r = scale * s;
    const int e = tid & 31, b = (tid >> 5) & 63, nn2 = tid >> 11;
    float* vp = vout + ((size_t)b * NN + nn2) * EE + e;
    if (ACCUM) *vp += r; else *vp = r;
}

// ---------------------------------------------------------------------------
extern "C" void kernel_launch(void* const* d_in, const int* in_sizes, int n_in,
                              void* d_out, int out_size, void* d_ws, size_t ws_size,
                              hipStream_t stream)
{
    const float* x = (const float*)d_in[0];
    const float* W = (const float*)d_in[1];
    float* ws      = (float*)d_ws;
    float* c_buf   = ws;                               // [I][N][B]  16 MB
    float* partial = ws + 4194304;                     // [32][N][B][E]  8 MB
    float* v_buf   = ws + 4194304 + 2097152;           // [B][N][E]  256 KB
    float* out     = (float*)d_out;

    const dim3 gw(NICB, 8);

    // round 0: c uniform = 1/32
    k_weighted_mfma<1><<<gw, 256, 0, stream>>>(x, W, nullptr, partial);
    k_squash_red<0><<<256, 256, 0, stream>>>(partial, v_buf);     // v0

    // round 1: logits vs v0
    k_logits_mfma<<<512, 256, 0, stream>>>(x, W, v_buf, c_buf);
    k_weighted_mfma<0><<<gw, 256, 0, stream>>>(x, W, c_buf, partial);
    k_squash_red<1><<<256, 256, 0, stream>>>(partial, v_buf);     // v0+v1

    // round 2: logits vs (v0+v1)  [b2 = sum_e u_hat*(v0+v1)]
    k_logits_mfma<<<512, 256, 0, stream>>>(x, W, v_buf, c_buf);
    k_weighted_mfma<0><<<gw, 256, 0, stream>>>(x, W, c_buf, partial);
    k_squash_red<0><<<256, 256, 0, stream>>>(partial, out);       // final v2
}

// Round 7
// 422.872 us; speedup vs baseline: 7.3667x; 1.0063x over previous
//
#include <hip/hip_runtime.h>
#include <hip/hip_bf16.h>
#include <math.h>

#define BB 64
#define II 2048
#define DD 16
#define NN 32
#define EE 32

typedef __bf16 bf16x8 __attribute__((ext_vector_type(8)));
typedef float  f32x16 __attribute__((ext_vector_type(16)));

static __device__ inline short f2bf_bits(float f) {
    union { __bf16 h; short s; } u; u.h = (__bf16)f; return u.s;
}

// ---------------------------------------------------------------------------
// k_weighted_mfma: partial[ic,n,b,e] = sum_{i in chunk, d} bf16(c[b,i,n]*x[b,i,d])
//                                      * bf16(W[i,n,d,e])
// MFMA 32x32x16 bf16: A = c*x (row=b=lane31 [+32/tile], k=d=8*half+j),
//                     B = W   (col=e=lane31, k=d=8*half+j),
//                     C: col=e=lane31, row b=(reg&3)+8*(reg>>2)+4*half (+32/tile)
// Grid (II/ICH, 8), 256 thr = 4 waves, wave owns n = ng*4 + w.
// ICH=16 -> 1024 blocks = 4 blocks/CU (TLP for latency hiding).
// ---------------------------------------------------------------------------
template<int UNIFORM, int ICH>
__global__ __launch_bounds__(256) void k_weighted_mfma(
    const float* __restrict__ x,      // [B][I][D]
    const float* __restrict__ Wg,     // [I][N][D][E]
    const float* __restrict__ c_buf,  // [I][N][B]  (ignored if UNIFORM)
    float* __restrict__ partial)      // [II/ICH][N][B][E]
{
    __shared__ short xl[8 * 64 * 24]; // chunk of 8 i's: [il][b][d, pad 24] bf16 bits

    const int ic     = blockIdx.x;
    const int ng     = blockIdx.y;    // 0..7
    const int t      = threadIdx.x;
    const int w      = t >> 6;
    const int n      = ng * 4 + w;
    const int lane31 = t & 31;
    const int half   = (t >> 5) & 1;
    const int i0     = ic * ICH;

    f32x16 acc0 = (f32x16)(0.0f), acc1 = (f32x16)(0.0f);

    for (int c8 = 0; c8 < ICH / 8; ++c8) {
        const int ib = i0 + c8 * 8;
        __syncthreads();
        // stage x[:, ib..ib+8, :] as bf16 (thread: b=t>>2, dg=(t&3)*4, loop il)
        {
            const int b = t >> 2, dg = (t & 3) * 4;
#pragma unroll
            for (int il = 0; il < 8; ++il) {
                const float4 xv = *(const float4*)(x + ((size_t)b * II + ib + il) * DD + dg);
                short4 s4;
                s4.x = f2bf_bits(xv.x); s4.y = f2bf_bits(xv.y);
                s4.z = f2bf_bits(xv.z); s4.w = f2bf_bits(xv.w);
                *(short4*)&xl[((il * 64 + b) * 24) + dg] = s4;
            }
        }
        __syncthreads();

        // prefetch c for the chunk (per-lane scalar, coalesced 128B per tile)
        float cf0[8], cf1[8];
        if (!UNIFORM) {
#pragma unroll
            for (int il = 0; il < 8; ++il) {
                const float* cp = c_buf + ((size_t)(ib + il) * NN + n) * BB + lane31;
                cf0[il] = cp[0];
                cf1[il] = cp[32];
            }
        }

#pragma unroll
        for (int il = 0; il < 8; ++il) {
            const int i = ib + il;
            // x fragments for both b-tiles (16B-aligned b128 reads)
            const bf16x8 xr0 = *(const bf16x8*)&xl[(il * 64 + lane31) * 24 + 8 * half];
            const bf16x8 xr1 = *(const bf16x8*)&xl[(il * 64 + 32 + lane31) * 24 + 8 * half];
            // W fragment (col = e = lane31, k = d = 8*half + j)
            const float* wp = Wg + (((size_t)i * NN + n) * DD + 8 * half) * EE + lane31;
            bf16x8 bw;
#pragma unroll
            for (int j = 0; j < 8; ++j) bw[j] = (__bf16)wp[j * EE];
            // A = bf16(c * x)
            const float c0 = UNIFORM ? 0.03125f : cf0[il];
            const float c1 = UNIFORM ? 0.03125f : cf1[il];
            bf16x8 a0, a1;
#pragma unroll
            for (int j = 0; j < 8; ++j) {
                a0[j] = (__bf16)(c0 * (float)xr0[j]);
                a1[j] = (__bf16)(c1 * (float)xr1[j]);
            }
            acc0 = __builtin_amdgcn_mfma_f32_32x32x16_bf16(a0, bw, acc0, 0, 0, 0);
            acc1 = __builtin_amdgcn_mfma_f32_32x32x16_bf16(a1, bw, acc1, 0, 0, 0);
        }
    }

    // store C-frags: row b = (reg&3)+8*(reg>>2)+4*half (+32 for tile 1), col e = lane31
    float* pp = partial + ((size_t)ic * NN + n) * BB * EE + lane31;
#pragma unroll
    for (int reg = 0; reg < 16; ++reg) {
        const int r = (reg & 3) + 8 * (reg >> 2) + 4 * half;
        pp[(size_t)r * EE]        = acc0[reg];
        pp[(size_t)(r + 32) * EE] = acc1[reg];
    }
}

// ---------------------------------------------------------------------------
// k_logits_mfma: c[i,n,b] = softmax_n( sum_e u_hat[b,i,n,e] * v[b,n,e] )
// One i per block now (grid 2048 = 8 blocks/CU for TLP).
// ---------------------------------------------------------------------------
__global__ __launch_bounds__(256) void k_logits_mfma(
    const float* __restrict__ x,      // [B][I][D]
    const float* __restrict__ Wg,     // [I][N][D][E]
    const float* __restrict__ v,      // [B][N][E]
    float* __restrict__ c_buf)        // [I][N][B]
{
    __shared__ short xl[BB][24];      // bf16 bits, padded stride
    __shared__ float al[BB][33];      // logits, padded

    const int t      = threadIdx.x;
    const int w      = t >> 6;        // wave 0..3
    const int lane31 = t & 31;
    const int half   = (t >> 5) & 1;
    const int i      = blockIdx.x;

    // stage x[:, i, :] as bf16
    {
        const int b = t >> 2, dg = (t & 3) * 4;
        const float4 xv = *(const float4*)(x + ((size_t)b * II + i) * DD + dg);
        short4 s4;
        s4.x = f2bf_bits(xv.x); s4.y = f2bf_bits(xv.y);
        s4.z = f2bf_bits(xv.z); s4.w = f2bf_bits(xv.w);
        *(short4*)&xl[b][dg] = s4;
    }
    __syncthreads();

    const bf16x8 bx0 = *(const bf16x8*)&xl[lane31][8 * half];
    const bf16x8 bx1 = *(const bf16x8*)&xl[32 + lane31][8 * half];

    for (int ci = 0; ci < 8; ++ci) {
        const int n = w * 8 + ci;
        const float* wp = Wg + (((size_t)i * NN + n) * DD + 8 * half) * EE + lane31;
        bf16x8 af;
#pragma unroll
        for (int j = 0; j < 8; ++j) af[j] = (__bf16)wp[j * EE];

#pragma unroll
        for (int m = 0; m < 2; ++m) {
            f32x16 cf = __builtin_amdgcn_mfma_f32_32x32x16_bf16(
                af, (m ? bx1 : bx0), (f32x16)(0.0f), 0, 0, 0);
            const float* vp = v + ((size_t)(32 * m + lane31) * NN + n) * EE + 4 * half;
            float acc = 0.f;
#pragma unroll
            for (int r2 = 0; r2 < 4; ++r2) {
                const float4 vv = *(const float4*)(vp + 8 * r2);
                acc += cf[r2 * 4 + 0] * vv.x + cf[r2 * 4 + 1] * vv.y
                     + cf[r2 * 4 + 2] * vv.z + cf[r2 * 4 + 3] * vv.w;
            }
            acc += __shfl_xor(acc, 32);           // merge e-halves
            if (half == 0) al[32 * m + lane31][n] = acc;
        }
    }
    __syncthreads();

    // softmax over n per b; write c[i][n][b] (coalesced across t per n)
    if (t < BB) {
        float a[NN]; float mx = -1e30f;
#pragma unroll
        for (int nn2 = 0; nn2 < NN; ++nn2) { a[nn2] = al[t][nn2]; mx = fmaxf(mx, a[nn2]); }
        float ssum = 0.f;
#pragma unroll
        for (int nn2 = 0; nn2 < NN; ++nn2) { a[nn2] = __expf(a[nn2] - mx); ssum += a[nn2]; }
        const float inv = 1.f / ssum;
        float* cp = c_buf + (size_t)i * NN * BB + t;
#pragma unroll
        for (int nn2 = 0; nn2 < NN; ++nn2) cp[(size_t)nn2 * BB] = a[nn2] * inv;
    }
}

// ---------------------------------------------------------------------------
// k_squash_red: s = sum_ic partial[ic]; v = squash(s). tid = n*2048+b*32+e.
// ACCUM=1 adds into vout (builds v0+v1). Writes vout[b][n][e].
// ---------------------------------------------------------------------------
template<int ACCUM, int NSLAB>
__global__ __launch_bounds__(256) void k_squash_red(
    const float* __restrict__ partial, float* __restrict__ vout)
{
    const int tid = blockIdx.x * 256 + threadIdx.x;   // 0..65535
    float s = 0.f;
#pragma unroll 8
    for (int ic = 0; ic < NSLAB; ++ic) s += partial[(size_t)ic * (NN * BB * EE) + tid];
    float sq = s * s;
    for (int msk = 16; msk >= 1; msk >>= 1) sq += __shfl_xor(sq, msk);
    const float scale = sq / (1.f + sq) * rsqrtf(sq + 1e-7f);
    const float r = scale * s;
    const int e = tid & 31, b = (tid >> 5) & 63, nn2 = tid >> 11;
    float* vp = vout + ((size_t)b * NN + nn2) * EE + e;
    if (ACCUM) *vp += r; else *vp = r;
}

// ---------------------------------------------------------------------------
extern "C" void kernel_launch(void* const* d_in, const int* in_sizes, int n_in,
                              void* d_out, int out_size, void* d_ws, size_t ws_size,
                              hipStream_t stream)
{
    const float* x = (const float*)d_in[0];
    const float* W = (const float*)d_in[1];
    float* ws      = (float*)d_ws;
    float* c_buf   = ws;                               // [I][N][B]  16 MB
    float* partial = ws + 4194304;
    float* out     = (float*)d_out;

    // Big config: ICH=16 -> 128 slabs (32 MB partial). Needs ~48.3 MB ws.
    const size_t need_big = (size_t)(4194304 + 128 * 65536 + 65536) * sizeof(float);

    if (ws_size >= need_big) {
        float* v_buf = ws + 4194304 + 128 * 65536;
        const dim3 gw(II / 16, 8);
        k_weighted_mfma<1, 16><<<gw, 256, 0, stream>>>(x, W, nullptr, partial);
        k_squash_red<0, 128><<<256, 256, 0, stream>>>(partial, v_buf);    // v0
        k_logits_mfma<<<II, 256, 0, stream>>>(x, W, v_buf, c_buf);
        k_weighted_mfma<0, 16><<<gw, 256, 0, stream>>>(x, W, c_buf, partial);
        k_squash_red<1, 128><<<256, 256, 0, stream>>>(partial, v_buf);    // v0+v1
        k_logits_mfma<<<II, 256, 0, stream>>>(x, W, v_buf, c_buf);
        k_weighted_mfma<0, 16><<<gw, 256, 0, stream>>>(x, W, c_buf, partial);
        k_squash_red<0, 128><<<256, 256, 0, stream>>>(partial, out);      // final v2
    } else {
        float* v_buf = ws + 4194304 + 32 * 65536;
        const dim3 gw(II / 64, 8);
        k_weighted_mfma<1, 64><<<gw, 256, 0, stream>>>(x, W, nullptr, partial);
        k_squash_red<0, 32><<<256, 256, 0, stream>>>(partial, v_buf);     // v0
        k_logits_mfma<<<II, 256, 0, stream>>>(x, W, v_buf, c_buf);
        k_weighted_mfma<0, 64><<<gw, 256, 0, stream>>>(x, W, c_buf, partial);
        k_squash_red<1, 32><<<256, 256, 0, stream>>>(partial, v_buf);     // v0+v1
        k_logits_mfma<<<II, 256, 0, stream>>>(x, W, v_buf, c_buf);
        k_weighted_mfma<0, 64><<<gw, 256, 0, stream>>>(x, W, c_buf, partial);
        k_squash_red<0, 32><<<256, 256, 0, stream>>>(partial, out);       // final v2
    }
}